// Round 9
// baseline (811.549 us; speedup 1.0000x reference)
//
#include <hip/hip_runtime.h>
#include <hip/hip_cooperative_groups.h>

namespace cg = cooperative_groups;

#define N_NODES 50000
#define N_EDGES 600000
#define DFEAT   128
#define SCAN_NB ((N_NODES + 255) / 256)   // 196 blocks of 256 counts

typedef __attribute__((ext_vector_type(8))) short short8;
typedef __attribute__((ext_vector_type(4))) float floatx4;

__device__ __forceinline__ unsigned short f2bf_rtne(float f) {
    unsigned b = __float_as_uint(f);
    return (unsigned short)((b + 0x7FFFu + ((b >> 16) & 1u)) >> 16);
}
__device__ __forceinline__ float bf2f(unsigned short u) {
    return __uint_as_float(((unsigned)u) << 16);
}

// ================= cooperative build kernel =================
// Phase A: zero cnt | x->bf16 table | W split/swizzle   (disjoint outputs)
// Phase B: histogram of dst
// Phase C: 3-phase exclusive scan (block partials kept in LDS across syncs)
// Phase D: fill sorted_src via cursor atomics
__global__ __launch_bounds__(256) void sage_build_kernel(
        const int* __restrict__ src, const int* __restrict__ dst,
        const float* __restrict__ x,
        const float* __restrict__ Ws0, const float* __restrict__ Wn0,
        const float* __restrict__ Ws1, const float* __restrict__ Wn1,
        const float* __restrict__ Ws2, const float* __restrict__ Wn2,
        unsigned short* __restrict__ Whi0, unsigned short* __restrict__ Wlo0,
        unsigned short* __restrict__ Whi1, unsigned short* __restrict__ Wlo1,
        unsigned short* __restrict__ Whi2, unsigned short* __restrict__ Wlo2,
        unsigned short* __restrict__ hb,
        int* __restrict__ cnt, int* __restrict__ bsum,
        int* __restrict__ row_ptr, int* __restrict__ cursor,
        float* __restrict__ invdeg, unsigned short* __restrict__ sorted_src)
{
    cg::grid_group grid = cg::this_grid();
    const int t = threadIdx.x;
    const int b = blockIdx.x;
    const int gtid = b * 256 + t;
    const int gsz  = gridDim.x * 256;

    // ---- Phase A ----
    for (int i = gtid; i < 50176; i += gsz) cnt[i] = 0;
    for (int i = gtid; i < N_NODES * DFEAT / 4; i += gsz) {
        float4 v = ((const float4*)x)[i];
        ushort4 o;
        o.x = f2bf_rtne(v.x); o.y = f2bf_rtne(v.y);
        o.z = f2bf_rtne(v.z); o.w = f2bf_rtne(v.w);
        ((ushort4*)hb)[i] = o;
    }
    if (gtid < 160 * 64) {   // weight prep: one (fid,lane) item per thread
        int fid_g = gtid >> 6;
        int lane  = gtid & 63;
        const float *Ws, *Wn;
        unsigned short *Whi, *Wlo;
        int N, fid;
        if (fid_g < 64)       { Ws = Ws0; Wn = Wn0; Whi = Whi0; Wlo = Wlo0; N = 128; fid = fid_g; }
        else if (fid_g < 128) { Ws = Ws1; Wn = Wn1; Whi = Whi1; Wlo = Wlo1; N = 128; fid = fid_g - 64; }
        else                  { Ws = Ws2; Wn = Wn2; Whi = Whi2; Wlo = Wlo2; N = 64;  fid = fid_g - 128; }
        int NT = N / 16;
        int kt = fid / NT, nt = fid % NT;
        int kbase = kt * 32 + (lane >> 4) * 8;
        int n = nt * 16 + (lane & 15);
        long base = ((long)fid * 64 + lane) * 8;
        #pragma unroll
        for (int j = 0; j < 8; j++) {
            int k = kbase + j;
            float w = (k < 128) ? Ws[k * N + n] : Wn[(k - 128) * N + n];
            unsigned bb = __float_as_uint(w);
            unsigned hib = bb & 0xFFFF0000u;
            float lo = w - __uint_as_float(hib);
            Whi[base + j] = (unsigned short)(bb >> 16);
            Wlo[base + j] = (unsigned short)(__float_as_uint(lo) >> 16);
        }
    }
    __threadfence();
    grid.sync();

    // ---- Phase B: histogram ----
    for (int e = gtid; e < N_EDGES; e += gsz) atomicAdd(&cnt[dst[e]], 1);
    __threadfence();
    grid.sync();

    // ---- Phase C1: block-local inclusive scan (kept in LDS) + block totals ----
    __shared__ int sincl[256];
    __shared__ int sw1[4];
    int v = 0;
    if (b < SCAN_NB) {
        int i = b * 256 + t;
        v = (i < N_NODES) ? cnt[i] : 0;
        int lane = t & 63, wid = t >> 6;
        int incl = v;
        #pragma unroll
        for (int off = 1; off < 64; off <<= 1) {
            int y = __shfl_up(incl, off);
            if (lane >= off) incl += y;
        }
        if (lane == 63) sw1[wid] = incl;
        __syncthreads();
        int wpre = 0;
        for (int w = 0; w < wid; w++) wpre += sw1[w];
        sincl[t] = wpre + incl;                  // block-inclusive prefix
        if (t == 255) bsum[b] = wpre + incl;     // block total
    }
    __threadfence();
    grid.sync();

    // ---- Phase C2: block 0 exclusive-scans the block totals ----
    if (b == 0) {
        __shared__ int sw2[4];
        int v2 = (t < SCAN_NB) ? bsum[t] : 0;
        int lane = t & 63, wid = t >> 6;
        int incl = v2;
        #pragma unroll
        for (int off = 1; off < 64; off <<= 1) {
            int y = __shfl_up(incl, off);
            if (lane >= off) incl += y;
        }
        if (lane == 63) sw2[wid] = incl;
        __syncthreads();
        int wpre = 0;
        for (int w = 0; w < wid; w++) wpre += sw2[w];
        if (t < SCAN_NB) bsum[t] = wpre + incl - v2;   // exclusive
    }
    __threadfence();
    grid.sync();

    // ---- Phase C3: emit row_ptr / cursor / invdeg ----
    if (b < SCAN_NB) {
        int i = b * 256 + t;
        int excl = bsum[b] + sincl[t] - v;
        if (i < N_NODES) {
            row_ptr[i] = excl;
            cursor[i]  = excl;
            invdeg[i]  = 1.0f / fmaxf((float)v, 1.0f);
        }
        if (i == N_NODES - 1) row_ptr[N_NODES] = excl + v;
    }
    __threadfence();
    grid.sync();

    // ---- Phase D: fill sorted_src ----
    for (int e = gtid; e < N_EDGES; e += gsz) {
        int p = atomicAdd(&cursor[dst[e]], 1);
        sorted_src[p] = (unsigned short)src[e];
    }
}

// ================= gather v2: paired-edge wave-per-node =================
// Lanes 0-31 process even-index edges, 32-63 odd; each lane loads ushort4
// (8B, 32 lanes = full 256B row). Cross-half combine via shfl_down(32).
__global__ __launch_bounds__(256) void sage_gather_kernel(
        const unsigned short* __restrict__ hb, const int* __restrict__ row_ptr,
        const unsigned short* __restrict__ sorted_src, const float* __restrict__ invdeg,
        unsigned short* __restrict__ mean_b, int nNodes)
{
    int node = blockIdx.x * 4 + (threadIdx.x >> 6);
    int lane = threadIdx.x & 63;
    if (node >= nNodes) return;
    const int half = lane >> 5;
    const int fq   = lane & 31;              // feature quad: feats fq*4..+3
    const int beg = row_ptr[node];
    const int end = row_ptr[node + 1];

    float4 s0 = make_float4(0.f, 0.f, 0.f, 0.f);
    float4 s1 = make_float4(0.f, 0.f, 0.f, 0.f);
    int e = beg + half;
    for (; e + 2 < end; e += 4) {
        int sA = sorted_src[e];
        int sB = sorted_src[e + 2];
        ushort4 vA = *(const ushort4*)(hb + (long)sA * DFEAT + fq * 4);
        ushort4 vB = *(const ushort4*)(hb + (long)sB * DFEAT + fq * 4);
        s0.x += bf2f(vA.x); s0.y += bf2f(vA.y); s0.z += bf2f(vA.z); s0.w += bf2f(vA.w);
        s1.x += bf2f(vB.x); s1.y += bf2f(vB.y); s1.z += bf2f(vB.z); s1.w += bf2f(vB.w);
    }
    for (; e < end; e += 2) {
        int sA = sorted_src[e];
        ushort4 vA = *(const ushort4*)(hb + (long)sA * DFEAT + fq * 4);
        s0.x += bf2f(vA.x); s0.y += bf2f(vA.y); s0.z += bf2f(vA.z); s0.w += bf2f(vA.w);
    }
    float sx = s0.x + s1.x, sy = s0.y + s1.y, sz = s0.z + s1.z, sw = s0.w + s1.w;
    sx += __shfl_down(sx, 32);
    sy += __shfl_down(sy, 32);
    sz += __shfl_down(sz, 32);
    sw += __shfl_down(sw, 32);
    if (half == 0) {
        float sc = invdeg[node];
        ushort4 r;
        r.x = f2bf_rtne(sx * sc); r.y = f2bf_rtne(sy * sc);
        r.z = f2bf_rtne(sz * sc); r.w = f2bf_rtne(sw * sc);
        *(ushort4*)(mean_b + (long)node * DFEAT + fq * 4) = r;
    }
}

// ================= MFMA dual-matmul + bias + relu =================
// Self path (kt 0..3): fp32 h, 3-term bf16 split. Mean path (kt 4..7): bf16
// mean read directly as A-frag (exact) -> 2 MFMAs. WB: emit bf16 copy of out.
template<int NT, bool RELU, bool WB>
__global__ __launch_bounds__(64) void sage_mm_mfma_kernel(
        const float* __restrict__ h, const unsigned short* __restrict__ mean_b,
        const unsigned short* __restrict__ Whi, const unsigned short* __restrict__ Wlo,
        const float* __restrict__ bias, float* __restrict__ out,
        unsigned short* __restrict__ hb_out, int M)
{
    constexpr int N = NT * 16;
    const int lane = threadIdx.x;
    const int q    = lane >> 4;
    const int l16  = lane & 15;
    const int rowbase = blockIdx.x * 32;

    floatx4 acc[2][NT];
    #pragma unroll
    for (int mt = 0; mt < 2; mt++)
        #pragma unroll
        for (int nt = 0; nt < NT; nt++)
            acc[mt][nt] = (floatx4){0.f, 0.f, 0.f, 0.f};

    int r0 = rowbase + l16;       if (r0 >= M) r0 = M - 1;
    int r1 = rowbase + 16 + l16;  if (r1 >= M) r1 = M - 1;
    const int rr[2] = {r0, r1};

    #pragma unroll
    for (int kt = 0; kt < 8; kt++) {
        const int koff = (kt & 3) * 32 + q * 8;

        if (kt < 4) {
            union { short8 v; unsigned u[4]; } ahi[2], alo[2];
            #pragma unroll
            for (int mt = 0; mt < 2; mt++) {
                const float* p = h + (long)rr[mt] * DFEAT + koff;
                float4 x0 = *(const float4*)p;
                float4 x1 = *(const float4*)(p + 4);
                float xs[8] = {x0.x, x0.y, x0.z, x0.w, x1.x, x1.y, x1.z, x1.w};
                #pragma unroll
                for (int pr = 0; pr < 4; pr++) {
                    unsigned b0 = __float_as_uint(xs[2 * pr]);
                    unsigned b1 = __float_as_uint(xs[2 * pr + 1]);
                    unsigned h0b = b0 & 0xFFFF0000u;
                    unsigned h1b = b1 & 0xFFFF0000u;
                    ahi[mt].u[pr] = (b0 >> 16) | h1b;
                    float l0 = xs[2 * pr]     - __uint_as_float(h0b);
                    float l1 = xs[2 * pr + 1] - __uint_as_float(h1b);
                    alo[mt].u[pr] = (__float_as_uint(l0) >> 16) |
                                    (__float_as_uint(l1) & 0xFFFF0000u);
                }
            }
            #pragma unroll
            for (int nt = 0; nt < NT; nt++) {
                long fb = ((long)(kt * NT + nt) * 64 + lane) * 8;
                short8 bhi = *(const short8*)(Whi + fb);
                short8 blo = *(const short8*)(Wlo + fb);
                #pragma unroll
                for (int mt = 0; mt < 2; mt++) {
                    acc[mt][nt] = __builtin_amdgcn_mfma_f32_16x16x32_bf16(ahi[mt].v, bhi, acc[mt][nt], 0, 0, 0);
                    acc[mt][nt] = __builtin_amdgcn_mfma_f32_16x16x32_bf16(alo[mt].v, bhi, acc[mt][nt], 0, 0, 0);
                    acc[mt][nt] = __builtin_amdgcn_mfma_f32_16x16x32_bf16(ahi[mt].v, blo, acc[mt][nt], 0, 0, 0);
                }
            }
        } else {
            short8 am[2];
            #pragma unroll
            for (int mt = 0; mt < 2; mt++)
                am[mt] = *(const short8*)(mean_b + (long)rr[mt] * DFEAT + koff);
            #pragma unroll
            for (int nt = 0; nt < NT; nt++) {
                long fb = ((long)(kt * NT + nt) * 64 + lane) * 8;
                short8 bhi = *(const short8*)(Whi + fb);
                short8 blo = *(const short8*)(Wlo + fb);
                #pragma unroll
                for (int mt = 0; mt < 2; mt++) {
                    acc[mt][nt] = __builtin_amdgcn_mfma_f32_16x16x32_bf16(am[mt], bhi, acc[mt][nt], 0, 0, 0);
                    acc[mt][nt] = __builtin_amdgcn_mfma_f32_16x16x32_bf16(am[mt], blo, acc[mt][nt], 0, 0, 0);
                }
            }
        }
    }

    #pragma unroll
    for (int nt = 0; nt < NT; nt++) {
        float bv = bias[nt * 16 + l16];
        #pragma unroll
        for (int mt = 0; mt < 2; mt++) {
            #pragma unroll
            for (int reg = 0; reg < 4; reg++) {
                int grow = rowbase + mt * 16 + q * 4 + reg;
                if (grow < M) {
                    float v = acc[mt][nt][reg] + bv;
                    if (RELU) v = fmaxf(v, 0.f);
                    long idx = (long)grow * N + nt * 16 + l16;
                    out[idx] = v;
                    if (WB) hb_out[idx] = f2bf_rtne(v);
                }
            }
        }
    }
}

extern "C" void kernel_launch(void* const* d_in, const int* in_sizes, int n_in,
                              void* d_out, int out_size, void* d_ws, size_t ws_size,
                              hipStream_t stream) {
    const float* x   = (const float*)d_in[0];
    const int*   ei  = (const int*)d_in[1];
    const float* Ws0 = (const float*)d_in[2];
    const float* Wn0 = (const float*)d_in[3];
    const float* b0  = (const float*)d_in[4];
    const float* Ws1 = (const float*)d_in[5];
    const float* Wn1 = (const float*)d_in[6];
    const float* b1  = (const float*)d_in[7];
    const float* Ws2 = (const float*)d_in[8];
    const float* Wn2 = (const float*)d_in[9];
    const float* b2  = (const float*)d_in[10];
    float* out = (float*)d_out;

    const int* src = ei;
    const int* dst = ei + N_EDGES;

    // ---- workspace layout ----
    char* ws = (char*)d_ws;
    float* invdeg     = (float*)ws;   ws += 50176 * 4;
    int*   cnt        = (int*)ws;     ws += 50176 * 4;
    int*   row_ptr    = (int*)ws;     ws += 50432 * 4;
    int*   cursor     = (int*)ws;     ws += 50432 * 4;
    int*   bsum       = (int*)ws;     ws += 256 * 4;
    unsigned short* sorted_src = (unsigned short*)ws; ws += 600064 * 2;
    unsigned short* Whi0 = (unsigned short*)ws; ws += 8 * 8 * 64 * 8 * 2;   // 64 KB
    unsigned short* Wlo0 = (unsigned short*)ws; ws += 8 * 8 * 64 * 8 * 2;
    unsigned short* Whi1 = (unsigned short*)ws; ws += 8 * 8 * 64 * 8 * 2;
    unsigned short* Wlo1 = (unsigned short*)ws; ws += 8 * 8 * 64 * 8 * 2;
    unsigned short* Whi2 = (unsigned short*)ws; ws += 8 * 4 * 64 * 8 * 2;   // 32 KB
    unsigned short* Wlo2 = (unsigned short*)ws; ws += 8 * 4 * 64 * 8 * 2;
    unsigned short* hb  = (unsigned short*)ws;  ws += (long)N_NODES * DFEAT * 2;  // 12.8 MB
    unsigned short* mean_b = (unsigned short*)ws; ws += (long)N_NODES * DFEAT * 2; // 12.8 MB
    float* h0         = (float*)ws;   ws += (long)N_NODES * DFEAT * 4;
    float* h1         = (float*)ws;

    // ---- single cooperative build kernel (prep + CSR) ----
    void* args[] = {
        (void*)&src, (void*)&dst, (void*)&x,
        (void*)&Ws0, (void*)&Wn0, (void*)&Ws1, (void*)&Wn1, (void*)&Ws2, (void*)&Wn2,
        (void*)&Whi0, (void*)&Wlo0, (void*)&Whi1, (void*)&Wlo1, (void*)&Whi2, (void*)&Wlo2,
        (void*)&hb,
        (void*)&cnt, (void*)&bsum, (void*)&row_ptr, (void*)&cursor,
        (void*)&invdeg, (void*)&sorted_src
    };
    hipLaunchCooperativeKernel((const void*)sage_build_kernel,
                               dim3(512), dim3(256), args, 0, stream);

    const int gather_blocks = (N_NODES + 3) / 4;   // wave per node
    const int mm_blocks = (N_NODES + 31) / 32;     // 1563 single-wave blocks

    // ---- layer 0 ----
    sage_gather_kernel<<<gather_blocks, 256, 0, stream>>>(
        hb, row_ptr, sorted_src, invdeg, mean_b, N_NODES);
    sage_mm_mfma_kernel<8, true, true><<<mm_blocks, 64, 0, stream>>>(
        x, mean_b, Whi0, Wlo0, b0, h0, hb, N_NODES);

    // ---- layer 1 ----
    sage_gather_kernel<<<gather_blocks, 256, 0, stream>>>(
        hb, row_ptr, sorted_src, invdeg, mean_b, N_NODES);
    sage_mm_mfma_kernel<8, true, true><<<mm_blocks, 64, 0, stream>>>(
        h0, mean_b, Whi1, Wlo1, b1, h1, hb, N_NODES);

    // ---- layer 2 ----
    sage_gather_kernel<<<gather_blocks, 256, 0, stream>>>(
        hb, row_ptr, sorted_src, invdeg, mean_b, N_NODES);
    sage_mm_mfma_kernel<4, false, false><<<mm_blocks, 64, 0, stream>>>(
        h1, mean_b, Whi2, Wlo2, b2, out, nullptr, N_NODES);
}

// Round 10
// 388.895 us; speedup vs baseline: 2.0868x; 2.0868x over previous
//
#include <hip/hip_runtime.h>

#define N_NODES 50000
#define N_EDGES 600000
#define DFEAT   128
#define SCAN_NB ((N_NODES + 255) / 256)   // 196 blocks of 256 counts

typedef __attribute__((ext_vector_type(8))) short short8;
typedef __attribute__((ext_vector_type(4))) float floatx4;

__device__ __forceinline__ unsigned short f2bf_rtne(float f) {
    unsigned b = __float_as_uint(f);
    return (unsigned short)((b + 0x7FFFu + ((b >> 16) & 1u)) >> 16);
}
__device__ __forceinline__ float bf2f(unsigned short u) {
    return __uint_as_float(((unsigned)u) << 16);
}

// ================= prep: zero cnt/ctr | x->bf16 table | W split/swizzle =========
// All outputs disjoint; no ordering needed within the kernel.
__global__ __launch_bounds__(256) void sage_prep_kernel(
        const float* __restrict__ x,
        const float* __restrict__ Ws0, const float* __restrict__ Wn0,
        const float* __restrict__ Ws1, const float* __restrict__ Wn1,
        const float* __restrict__ Ws2, const float* __restrict__ Wn2,
        unsigned short* __restrict__ Whi0, unsigned short* __restrict__ Wlo0,
        unsigned short* __restrict__ Whi1, unsigned short* __restrict__ Wlo1,
        unsigned short* __restrict__ Whi2, unsigned short* __restrict__ Wlo2,
        unsigned short* __restrict__ hb, int* __restrict__ cnt,
        unsigned* __restrict__ ctr)
{
    const int gtid = blockIdx.x * 256 + threadIdx.x;
    const int gsz  = gridDim.x * 256;
    if (gtid == 0) *ctr = 0u;
    for (int i = gtid; i < 50176; i += gsz) cnt[i] = 0;
    for (int i = gtid; i < N_NODES * DFEAT / 4; i += gsz) {
        float4 v = ((const float4*)x)[i];
        ushort4 o;
        o.x = f2bf_rtne(v.x); o.y = f2bf_rtne(v.y);
        o.z = f2bf_rtne(v.z); o.w = f2bf_rtne(v.w);
        ((ushort4*)hb)[i] = o;
    }
    for (int it = gtid; it < 160 * 64; it += gsz) {
        int fid_g = it >> 6;
        int lane  = it & 63;
        const float *Ws, *Wn;
        unsigned short *Whi, *Wlo;
        int N, fid;
        if (fid_g < 64)       { Ws = Ws0; Wn = Wn0; Whi = Whi0; Wlo = Wlo0; N = 128; fid = fid_g; }
        else if (fid_g < 128) { Ws = Ws1; Wn = Wn1; Whi = Whi1; Wlo = Wlo1; N = 128; fid = fid_g - 64; }
        else                  { Ws = Ws2; Wn = Wn2; Whi = Whi2; Wlo = Wlo2; N = 64;  fid = fid_g - 128; }
        int NT = N / 16;
        int kt = fid / NT, nt = fid % NT;
        int kbase = kt * 32 + (lane >> 4) * 8;
        int n = nt * 16 + (lane & 15);
        long base = ((long)fid * 64 + lane) * 8;
        #pragma unroll
        for (int j = 0; j < 8; j++) {
            int k = kbase + j;
            float w = (k < 128) ? Ws[k * N + n] : Wn[(k - 128) * N + n];
            unsigned bb = __float_as_uint(w);
            unsigned hib = bb & 0xFFFF0000u;
            float lo = w - __uint_as_float(hib);
            Whi[base + j] = (unsigned short)(bb >> 16);
            Wlo[base + j] = (unsigned short)(__float_as_uint(lo) >> 16);
        }
    }
}

// ================= histogram of dst =================
__global__ void sage_hist_kernel(const int* __restrict__ dst, int* __restrict__ cnt, int nE) {
    int e = blockIdx.x * blockDim.x + threadIdx.x;
    if (e < nE) atomicAdd(&cnt[dst[e]], 1);
}

// ================= per-tile sums + last-block exclusive scan of totals =========
__global__ __launch_bounds__(256) void sage_bsum_kernel(
        const int* __restrict__ cnt, int* __restrict__ bsum,
        unsigned* __restrict__ ctr, int n, int nb) {
    const int t = threadIdx.x;
    int i = blockIdx.x * 256 + t;
    int v = (i < n) ? cnt[i] : 0;
    int r = v;
    #pragma unroll
    for (int off = 32; off > 0; off >>= 1) r += __shfl_down(r, off);
    __shared__ int ws4[4];
    __shared__ int lastflag;
    if ((t & 63) == 0) ws4[t >> 6] = r;
    __syncthreads();
    if (t == 0) {
        bsum[blockIdx.x] = ws4[0] + ws4[1] + ws4[2] + ws4[3];
        __threadfence();
        unsigned old = atomicAdd(ctr, 1u);
        lastflag = (old == (unsigned)(nb - 1)) ? 1 : 0;
    }
    __syncthreads();
    if (lastflag) {   // block-uniform: whole last block scans the totals
        __threadfence();
        int v2 = (t < nb) ? bsum[t] : 0;
        int lane = t & 63, wid = t >> 6;
        int incl = v2;
        #pragma unroll
        for (int off = 1; off < 64; off <<= 1) {
            int y = __shfl_up(incl, off);
            if (lane >= off) incl += y;
        }
        __shared__ int sw2[4];
        if (lane == 63) sw2[wid] = incl;
        __syncthreads();
        int wpre = 0;
        for (int w = 0; w < wid; w++) wpre += sw2[w];
        if (t < nb) bsum[t] = wpre + incl - v2;   // exclusive
    }
}

// ================= per-block scan + offset -> row_ptr/cursor/invdeg =========
__global__ __launch_bounds__(256) void sage_scan2_kernel(
        const int* __restrict__ cnt, const int* __restrict__ bscan,
        int* __restrict__ row_ptr, int* __restrict__ cursor,
        float* __restrict__ invdeg, int n) {
    int i = blockIdx.x * 256 + threadIdx.x;
    int v = (i < n) ? cnt[i] : 0;
    int lane = threadIdx.x & 63, wid = threadIdx.x >> 6;
    int incl = v;
    #pragma unroll
    for (int off = 1; off < 64; off <<= 1) {
        int y = __shfl_up(incl, off);
        if (lane >= off) incl += y;
    }
    __shared__ int ws[4];
    if (lane == 63) ws[wid] = incl;
    __syncthreads();
    int wpre = 0;
    for (int w = 0; w < wid; w++) wpre += ws[w];
    int excl = bscan[blockIdx.x] + wpre + incl - v;
    if (i < n) {
        row_ptr[i] = excl;
        cursor[i]  = excl;
        invdeg[i]  = 1.0f / fmaxf((float)v, 1.0f);
    }
    if (i == n - 1) row_ptr[n] = excl + v;
}

// ================= fill sorted_src (ushort) via cursor =================
__global__ void sage_fill_kernel(const int* __restrict__ src, const int* __restrict__ dst,
                                 int* __restrict__ cursor,
                                 unsigned short* __restrict__ sorted_src, int nE) {
    int e = blockIdx.x * blockDim.x + threadIdx.x;
    if (e < nE) {
        int p = atomicAdd(&cursor[dst[e]], 1);
        sorted_src[p] = (unsigned short)src[e];
    }
}

// ================= fused gather + MFMA layer kernel =================
// Block = 256 threads = 4 waves, owns 32 nodes.
// Phase 1: wave w gathers nodes base+w*8..+8 (wave-per-node, lane=2 feats,
//          same summation order as before) -> bf16 mean in LDS (stride 136).
// Phase 2: wave w computes output quadrant (rows mt*16..+16, cols ch*N/2..):
//          self path = fp32 h 3-term bf16 split; mean path = LDS bf16 A-frag
//          (exact, 2 MFMAs). WB: bf16 copy of out into hb_out (ping-pong).
template<int NT_TOTAL, bool RELU, bool WB>
__global__ __launch_bounds__(256) void sage_layer_kernel(
        const float* __restrict__ h, const unsigned short* __restrict__ hb_in,
        const int* __restrict__ row_ptr, const unsigned short* __restrict__ sorted_src,
        const float* __restrict__ invdeg,
        const unsigned short* __restrict__ Whi, const unsigned short* __restrict__ Wlo,
        const float* __restrict__ bias, float* __restrict__ out,
        unsigned short* __restrict__ hb_out, int M)
{
    constexpr int N   = NT_TOTAL * 16;
    constexpr int NTW = NT_TOTAL / 2;     // col tiles per wave
    constexpr int LDM = 136;              // LDS row stride (ushorts), 16B-aligned

    __shared__ unsigned short mean_s[32 * LDM];

    const int t    = threadIdx.x;
    const int w    = t >> 6;
    const int lane = t & 63;
    const int base = blockIdx.x * 32;
    const ushort2* hb2 = (const ushort2*)hb_in;

    // ---- phase 1: gather ----
    #pragma unroll 1
    for (int j = 0; j < 8; j++) {
        int node = base + w * 8 + j;
        if (node < M) {
            int nl = w * 8 + j;
            const int beg = row_ptr[node];
            const int end = row_ptr[node + 1];
            float a0 = 0.f, a1 = 0.f, a2 = 0.f, a3 = 0.f;
            float c0 = 0.f, c1 = 0.f, c2 = 0.f, c3 = 0.f;
            int e = beg;
            for (; e + 4 <= end; e += 4) {
                int s0 = sorted_src[e];
                int s1 = sorted_src[e + 1];
                int s2 = sorted_src[e + 2];
                int s3 = sorted_src[e + 3];
                ushort2 v0 = hb2[(long)s0 * 64 + lane];
                ushort2 v1 = hb2[(long)s1 * 64 + lane];
                ushort2 v2 = hb2[(long)s2 * 64 + lane];
                ushort2 v3 = hb2[(long)s3 * 64 + lane];
                a0 += bf2f(v0.x); c0 += bf2f(v0.y);
                a1 += bf2f(v1.x); c1 += bf2f(v1.y);
                a2 += bf2f(v2.x); c2 += bf2f(v2.y);
                a3 += bf2f(v3.x); c3 += bf2f(v3.y);
            }
            for (; e < end; e++) {
                ushort2 v = hb2[(long)sorted_src[e] * 64 + lane];
                a0 += bf2f(v.x); c0 += bf2f(v.y);
            }
            float sc = invdeg[node];
            ushort2 r;
            r.x = f2bf_rtne((a0 + a1 + a2 + a3) * sc);
            r.y = f2bf_rtne((c0 + c1 + c2 + c3) * sc);
            *(ushort2*)&mean_s[nl * LDM + lane * 2] = r;
        }
    }
    __syncthreads();

    // ---- phase 2: MFMA quadrant ----
    const int mt = w & 1;                 // row half
    const int ch = w >> 1;                // col half
    const int q = lane >> 4, l16 = lane & 15;

    floatx4 acc[NTW];
    #pragma unroll
    for (int ntw = 0; ntw < NTW; ntw++) acc[ntw] = (floatx4){0.f, 0.f, 0.f, 0.f};

    int r = base + mt * 16 + l16;  if (r >= M) r = M - 1;

    #pragma unroll
    for (int kt = 0; kt < 4; kt++) {       // self path: fp32 h, 3-term split
        const int koff = kt * 32 + q * 8;
        const float* p = h + (long)r * DFEAT + koff;
        float4 x0 = *(const float4*)p;
        float4 x1 = *(const float4*)(p + 4);
        float xs[8] = {x0.x, x0.y, x0.z, x0.w, x1.x, x1.y, x1.z, x1.w};
        union { short8 v; unsigned u[4]; } ahi, alo;
        #pragma unroll
        for (int pr = 0; pr < 4; pr++) {
            unsigned b0 = __float_as_uint(xs[2 * pr]);
            unsigned b1 = __float_as_uint(xs[2 * pr + 1]);
            unsigned h0b = b0 & 0xFFFF0000u;
            unsigned h1b = b1 & 0xFFFF0000u;
            ahi.u[pr] = (b0 >> 16) | h1b;
            float l0 = xs[2 * pr]     - __uint_as_float(h0b);
            float l1 = xs[2 * pr + 1] - __uint_as_float(h1b);
            alo.u[pr] = (__float_as_uint(l0) >> 16) |
                        (__float_as_uint(l1) & 0xFFFF0000u);
        }
        #pragma unroll
        for (int ntw = 0; ntw < NTW; ntw++) {
            int nt = ch * NTW + ntw;
            long fb = ((long)(kt * NT_TOTAL + nt) * 64 + lane) * 8;
            short8 bhi = *(const short8*)(Whi + fb);
            short8 blo = *(const short8*)(Wlo + fb);
            acc[ntw] = __builtin_amdgcn_mfma_f32_16x16x32_bf16(ahi.v, bhi, acc[ntw], 0, 0, 0);
            acc[ntw] = __builtin_amdgcn_mfma_f32_16x16x32_bf16(alo.v, bhi, acc[ntw], 0, 0, 0);
            acc[ntw] = __builtin_amdgcn_mfma_f32_16x16x32_bf16(ahi.v, blo, acc[ntw], 0, 0, 0);
        }
    }
    #pragma unroll
    for (int kt = 4; kt < 8; kt++) {       // mean path: bf16 A-frag from LDS
        const int koff = (kt - 4) * 32 + q * 8;
        short8 am = *(const short8*)&mean_s[(mt * 16 + l16) * LDM + koff];
        #pragma unroll
        for (int ntw = 0; ntw < NTW; ntw++) {
            int nt = ch * NTW + ntw;
            long fb = ((long)(kt * NT_TOTAL + nt) * 64 + lane) * 8;
            short8 bhi = *(const short8*)(Whi + fb);
            short8 blo = *(const short8*)(Wlo + fb);
            acc[ntw] = __builtin_amdgcn_mfma_f32_16x16x32_bf16(am, bhi, acc[ntw], 0, 0, 0);
            acc[ntw] = __builtin_amdgcn_mfma_f32_16x16x32_bf16(am, blo, acc[ntw], 0, 0, 0);
        }
    }

    // ---- epilogue ----
    #pragma unroll
    for (int ntw = 0; ntw < NTW; ntw++) {
        int nt = ch * NTW + ntw;
        float bv = bias[nt * 16 + l16];
        #pragma unroll
        for (int reg = 0; reg < 4; reg++) {
            int grow = base + mt * 16 + q * 4 + reg;
            if (grow < M) {
                float v = acc[ntw][reg] + bv;
                if (RELU) v = fmaxf(v, 0.f);
                long idx = (long)grow * N + nt * 16 + l16;
                out[idx] = v;
                if (WB) hb_out[idx] = f2bf_rtne(v);
            }
        }
    }
}

extern "C" void kernel_launch(void* const* d_in, const int* in_sizes, int n_in,
                              void* d_out, int out_size, void* d_ws, size_t ws_size,
                              hipStream_t stream) {
    const float* x   = (const float*)d_in[0];
    const int*   ei  = (const int*)d_in[1];
    const float* Ws0 = (const float*)d_in[2];
    const float* Wn0 = (const float*)d_in[3];
    const float* b0  = (const float*)d_in[4];
    const float* Ws1 = (const float*)d_in[5];
    const float* Wn1 = (const float*)d_in[6];
    const float* b1  = (const float*)d_in[7];
    const float* Ws2 = (const float*)d_in[8];
    const float* Wn2 = (const float*)d_in[9];
    const float* b2  = (const float*)d_in[10];
    float* out = (float*)d_out;

    const int* src = ei;
    const int* dst = ei + N_EDGES;

    // ---- workspace layout ----
    char* ws = (char*)d_ws;
    float* invdeg     = (float*)ws;   ws += 50176 * 4;
    int*   cnt        = (int*)ws;     ws += 50176 * 4;
    int*   row_ptr    = (int*)ws;     ws += 50432 * 4;
    int*   cursor     = (int*)ws;     ws += 50432 * 4;
    int*   bsum       = (int*)ws;     ws += 256 * 4;
    unsigned* ctr     = (unsigned*)ws; ws += 256 * 4;
    unsigned short* sorted_src = (unsigned short*)ws; ws += 600064 * 2;
    unsigned short* Whi0 = (unsigned short*)ws; ws += 8 * 8 * 64 * 8 * 2;   // 64 KB
    unsigned short* Wlo0 = (unsigned short*)ws; ws += 8 * 8 * 64 * 8 * 2;
    unsigned short* Whi1 = (unsigned short*)ws; ws += 8 * 8 * 64 * 8 * 2;
    unsigned short* Wlo1 = (unsigned short*)ws; ws += 8 * 8 * 64 * 8 * 2;
    unsigned short* Whi2 = (unsigned short*)ws; ws += 8 * 4 * 64 * 8 * 2;   // 32 KB
    unsigned short* Wlo2 = (unsigned short*)ws; ws += 8 * 4 * 64 * 8 * 2;
    unsigned short* hb_a = (unsigned short*)ws; ws += (long)N_NODES * DFEAT * 2; // 12.8 MB
    unsigned short* hb_b = (unsigned short*)ws; ws += (long)N_NODES * DFEAT * 2; // 12.8 MB
    float* h0         = (float*)ws;   ws += (long)N_NODES * DFEAT * 4;
    float* h1         = (float*)ws;

    // ---- build chain (5 dispatches) ----
    sage_prep_kernel<<<1024, 256, 0, stream>>>(
        x, Ws0, Wn0, Ws1, Wn1, Ws2, Wn2,
        Whi0, Wlo0, Whi1, Wlo1, Whi2, Wlo2, hb_a, cnt, ctr);
    sage_hist_kernel<<<(N_EDGES + 255) / 256, 256, 0, stream>>>(dst, cnt, N_EDGES);
    sage_bsum_kernel<<<SCAN_NB, 256, 0, stream>>>(cnt, bsum, ctr, N_NODES, SCAN_NB);
    sage_scan2_kernel<<<SCAN_NB, 256, 0, stream>>>(cnt, bsum, row_ptr, cursor, invdeg, N_NODES);
    sage_fill_kernel<<<(N_EDGES + 255) / 256, 256, 0, stream>>>(
        src, dst, cursor, sorted_src, N_EDGES);

    const int layer_blocks = (N_NODES + 31) / 32;   // 1563

    // ---- fused layers (3 dispatches); hb ping-pong avoids intra-kernel RAW ----
    sage_layer_kernel<8, true, true><<<layer_blocks, 256, 0, stream>>>(
        x, hb_a, row_ptr, sorted_src, invdeg, Whi0, Wlo0, b0, h0, hb_b, N_NODES);
    sage_layer_kernel<8, true, true><<<layer_blocks, 256, 0, stream>>>(
        h0, hb_b, row_ptr, sorted_src, invdeg, Whi1, Wlo1, b1, h1, hb_a, N_NODES);
    sage_layer_kernel<4, false, false><<<layer_blocks, 256, 0, stream>>>(
        h1, hb_a, row_ptr, sorted_src, invdeg, Whi2, Wlo2, b2, out, nullptr, N_NODES);
}

// Round 11
// 326.733 us; speedup vs baseline: 2.4838x; 1.1903x over previous
//
#include <hip/hip_runtime.h>

#define N_NODES 50000
#define N_EDGES 600000
#define DFEAT   128
#define SCAN_NB ((N_NODES + 255) / 256)   // 196 blocks of 256 counts

typedef __attribute__((ext_vector_type(8))) short short8;
typedef __attribute__((ext_vector_type(4))) float floatx4;

__device__ __forceinline__ unsigned short f2bf_rtne(float f) {
    unsigned b = __float_as_uint(f);
    return (unsigned short)((b + 0x7FFFu + ((b >> 16) & 1u)) >> 16);
}
__device__ __forceinline__ float bf2f(unsigned short u) {
    return __uint_as_float(((unsigned)u) << 16);
}

// ================= prep: zero cnt/ctr | x->bf16 table | W split/swizzle =========
__global__ __launch_bounds__(256) void sage_prep_kernel(
        const float* __restrict__ x,
        const float* __restrict__ Ws0, const float* __restrict__ Wn0,
        const float* __restrict__ Ws1, const float* __restrict__ Wn1,
        const float* __restrict__ Ws2, const float* __restrict__ Wn2,
        unsigned short* __restrict__ Whi0, unsigned short* __restrict__ Wlo0,
        unsigned short* __restrict__ Whi1, unsigned short* __restrict__ Wlo1,
        unsigned short* __restrict__ Whi2, unsigned short* __restrict__ Wlo2,
        unsigned short* __restrict__ hb, int* __restrict__ cnt,
        unsigned* __restrict__ ctr)
{
    const int gtid = blockIdx.x * 256 + threadIdx.x;
    const int gsz  = gridDim.x * 256;
    if (gtid == 0) *ctr = 0u;
    for (int i = gtid; i < 50176; i += gsz) cnt[i] = 0;
    for (int i = gtid; i < N_NODES * DFEAT / 4; i += gsz) {
        float4 v = ((const float4*)x)[i];
        ushort4 o;
        o.x = f2bf_rtne(v.x); o.y = f2bf_rtne(v.y);
        o.z = f2bf_rtne(v.z); o.w = f2bf_rtne(v.w);
        ((ushort4*)hb)[i] = o;
    }
    for (int it = gtid; it < 160 * 64; it += gsz) {
        int fid_g = it >> 6;
        int lane  = it & 63;
        const float *Ws, *Wn;
        unsigned short *Whi, *Wlo;
        int N, fid;
        if (fid_g < 64)       { Ws = Ws0; Wn = Wn0; Whi = Whi0; Wlo = Wlo0; N = 128; fid = fid_g; }
        else if (fid_g < 128) { Ws = Ws1; Wn = Wn1; Whi = Whi1; Wlo = Wlo1; N = 128; fid = fid_g - 64; }
        else                  { Ws = Ws2; Wn = Wn2; Whi = Whi2; Wlo = Wlo2; N = 64;  fid = fid_g - 128; }
        int NT = N / 16;
        int kt = fid / NT, nt = fid % NT;
        int kbase = kt * 32 + (lane >> 4) * 8;
        int n = nt * 16 + (lane & 15);
        long base = ((long)fid * 64 + lane) * 8;
        #pragma unroll
        for (int j = 0; j < 8; j++) {
            int k = kbase + j;
            float w = (k < 128) ? Ws[k * N + n] : Wn[(k - 128) * N + n];
            unsigned bb = __float_as_uint(w);
            unsigned hib = bb & 0xFFFF0000u;
            float lo = w - __uint_as_float(hib);
            Whi[base + j] = (unsigned short)(bb >> 16);
            Wlo[base + j] = (unsigned short)(__float_as_uint(lo) >> 16);
        }
    }
}

// ================= histogram of dst =================
__global__ void sage_hist_kernel(const int* __restrict__ dst, int* __restrict__ cnt, int nE) {
    int e = blockIdx.x * blockDim.x + threadIdx.x;
    if (e < nE) atomicAdd(&cnt[dst[e]], 1);
}

// ================= per-tile sums + last-block exclusive scan of totals =========
__global__ __launch_bounds__(256) void sage_bsum_kernel(
        const int* __restrict__ cnt, int* __restrict__ bsum,
        unsigned* __restrict__ ctr, int n, int nb) {
    const int t = threadIdx.x;
    int i = blockIdx.x * 256 + t;
    int v = (i < n) ? cnt[i] : 0;
    int r = v;
    #pragma unroll
    for (int off = 32; off > 0; off >>= 1) r += __shfl_down(r, off);
    __shared__ int ws4[4];
    __shared__ int lastflag;
    if ((t & 63) == 0) ws4[t >> 6] = r;
    __syncthreads();
    if (t == 0) {
        bsum[blockIdx.x] = ws4[0] + ws4[1] + ws4[2] + ws4[3];
        __threadfence();
        unsigned old = atomicAdd(ctr, 1u);
        lastflag = (old == (unsigned)(nb - 1)) ? 1 : 0;
    }
    __syncthreads();
    if (lastflag) {   // block-uniform: whole last block scans the totals
        __threadfence();
        int v2 = (t < nb) ? bsum[t] : 0;
        int lane = t & 63, wid = t >> 6;
        int incl = v2;
        #pragma unroll
        for (int off = 1; off < 64; off <<= 1) {
            int y = __shfl_up(incl, off);
            if (lane >= off) incl += y;
        }
        __shared__ int sw2[4];
        if (lane == 63) sw2[wid] = incl;
        __syncthreads();
        int wpre = 0;
        for (int w = 0; w < wid; w++) wpre += sw2[w];
        if (t < nb) bsum[t] = wpre + incl - v2;   // exclusive
    }
}

// ================= per-block scan + offset -> row_ptr/cursor/invdeg =========
__global__ __launch_bounds__(256) void sage_scan2_kernel(
        const int* __restrict__ cnt, const int* __restrict__ bscan,
        int* __restrict__ row_ptr, int* __restrict__ cursor,
        float* __restrict__ invdeg, int n) {
    int i = blockIdx.x * 256 + threadIdx.x;
    int v = (i < n) ? cnt[i] : 0;
    int lane = threadIdx.x & 63, wid = threadIdx.x >> 6;
    int incl = v;
    #pragma unroll
    for (int off = 1; off < 64; off <<= 1) {
        int y = __shfl_up(incl, off);
        if (lane >= off) incl += y;
    }
    __shared__ int ws[4];
    if (lane == 63) ws[wid] = incl;
    __syncthreads();
    int wpre = 0;
    for (int w = 0; w < wid; w++) wpre += ws[w];
    int excl = bscan[blockIdx.x] + wpre + incl - v;
    if (i < n) {
        row_ptr[i] = excl;
        cursor[i]  = excl;
        invdeg[i]  = 1.0f / fmaxf((float)v, 1.0f);
    }
    if (i == n - 1) row_ptr[n] = excl + v;
}

// ================= fill sorted_src (ushort) via cursor =================
__global__ void sage_fill_kernel(const int* __restrict__ src, const int* __restrict__ dst,
                                 int* __restrict__ cursor,
                                 unsigned short* __restrict__ sorted_src, int nE) {
    int e = blockIdx.x * blockDim.x + threadIdx.x;
    if (e < nE) {
        int p = atomicAdd(&cursor[dst[e]], 1);
        sorted_src[p] = (unsigned short)src[e];
    }
}

// ================= gather: paired-edge wave-per-node (r8 form) =================
// Lanes 0-31 process even-index edges, 32-63 odd; each lane loads ushort4
// (8B, 32 lanes = full 256B row). Cross-half combine via shfl_down(32).
__global__ __launch_bounds__(256) void sage_gather_kernel(
        const unsigned short* __restrict__ hb, const int* __restrict__ row_ptr,
        const unsigned short* __restrict__ sorted_src, const float* __restrict__ invdeg,
        unsigned short* __restrict__ mean_b, int nNodes)
{
    int node = blockIdx.x * 4 + (threadIdx.x >> 6);
    int lane = threadIdx.x & 63;
    if (node >= nNodes) return;
    const int half = lane >> 5;
    const int fq   = lane & 31;              // feature quad: feats fq*4..+3
    const int beg = row_ptr[node];
    const int end = row_ptr[node + 1];

    float4 s0 = make_float4(0.f, 0.f, 0.f, 0.f);
    float4 s1 = make_float4(0.f, 0.f, 0.f, 0.f);
    int e = beg + half;
    for (; e + 2 < end; e += 4) {
        int sA = sorted_src[e];
        int sB = sorted_src[e + 2];
        ushort4 vA = *(const ushort4*)(hb + (long)sA * DFEAT + fq * 4);
        ushort4 vB = *(const ushort4*)(hb + (long)sB * DFEAT + fq * 4);
        s0.x += bf2f(vA.x); s0.y += bf2f(vA.y); s0.z += bf2f(vA.z); s0.w += bf2f(vA.w);
        s1.x += bf2f(vB.x); s1.y += bf2f(vB.y); s1.z += bf2f(vB.z); s1.w += bf2f(vB.w);
    }
    for (; e < end; e += 2) {
        int sA = sorted_src[e];
        ushort4 vA = *(const ushort4*)(hb + (long)sA * DFEAT + fq * 4);
        s0.x += bf2f(vA.x); s0.y += bf2f(vA.y); s0.z += bf2f(vA.z); s0.w += bf2f(vA.w);
    }
    float sx = s0.x + s1.x, sy = s0.y + s1.y, sz = s0.z + s1.z, sw = s0.w + s1.w;
    sx += __shfl_down(sx, 32);
    sy += __shfl_down(sy, 32);
    sz += __shfl_down(sz, 32);
    sw += __shfl_down(sw, 32);
    if (half == 0) {
        float sc = invdeg[node];
        ushort4 r;
        r.x = f2bf_rtne(sx * sc); r.y = f2bf_rtne(sy * sc);
        r.z = f2bf_rtne(sz * sc); r.w = f2bf_rtne(sw * sc);
        *(ushort4*)(mean_b + (long)node * DFEAT + fq * 4) = r;
    }
}

// ================= all-bf16 MFMA dual-matmul + bias + relu =================
// Self path (kt 0..3): bf16 table read directly as A-frag (exact, 2 MFMAs).
// Mean path (kt 4..7): bf16 mean A-frag (exact, 2 MFMAs).
// FINAL: write fp32 out; else write bf16 table for the next layer.
template<int NT, bool RELU, bool FINAL>
__global__ __launch_bounds__(64) void sage_mm_mfma_kernel(
        const unsigned short* __restrict__ hb_self, const unsigned short* __restrict__ mean_b,
        const unsigned short* __restrict__ Whi, const unsigned short* __restrict__ Wlo,
        const float* __restrict__ bias, float* __restrict__ out,
        unsigned short* __restrict__ hb_out, int M)
{
    constexpr int N = NT * 16;
    const int lane = threadIdx.x;
    const int q    = lane >> 4;
    const int l16  = lane & 15;
    const int rowbase = blockIdx.x * 32;

    floatx4 acc[2][NT];
    #pragma unroll
    for (int mt = 0; mt < 2; mt++)
        #pragma unroll
        for (int nt = 0; nt < NT; nt++)
            acc[mt][nt] = (floatx4){0.f, 0.f, 0.f, 0.f};

    int r0 = rowbase + l16;       if (r0 >= M) r0 = M - 1;
    int r1 = rowbase + 16 + l16;  if (r1 >= M) r1 = M - 1;
    const int rr[2] = {r0, r1};

    #pragma unroll
    for (int kt = 0; kt < 8; kt++) {
        const int koff = (kt & 3) * 32 + q * 8;
        const unsigned short* srcb = (kt < 4) ? hb_self : mean_b;
        short8 am[2];
        #pragma unroll
        for (int mt = 0; mt < 2; mt++)
            am[mt] = *(const short8*)(srcb + (long)rr[mt] * DFEAT + koff);
        #pragma unroll
        for (int nt = 0; nt < NT; nt++) {
            long fb = ((long)(kt * NT + nt) * 64 + lane) * 8;
            short8 bhi = *(const short8*)(Whi + fb);
            short8 blo = *(const short8*)(Wlo + fb);
            #pragma unroll
            for (int mt = 0; mt < 2; mt++) {
                acc[mt][nt] = __builtin_amdgcn_mfma_f32_16x16x32_bf16(am[mt], bhi, acc[mt][nt], 0, 0, 0);
                acc[mt][nt] = __builtin_amdgcn_mfma_f32_16x16x32_bf16(am[mt], blo, acc[mt][nt], 0, 0, 0);
            }
        }
    }

    #pragma unroll
    for (int nt = 0; nt < NT; nt++) {
        float bv = bias[nt * 16 + l16];
        #pragma unroll
        for (int mt = 0; mt < 2; mt++) {
            #pragma unroll
            for (int reg = 0; reg < 4; reg++) {
                int grow = rowbase + mt * 16 + q * 4 + reg;
                if (grow < M) {
                    float v = acc[mt][nt][reg] + bv;
                    if (RELU) v = fmaxf(v, 0.f);
                    long idx = (long)grow * N + nt * 16 + l16;
                    if (FINAL) out[idx] = v;
                    else       hb_out[idx] = f2bf_rtne(v);
                }
            }
        }
    }
}

extern "C" void kernel_launch(void* const* d_in, const int* in_sizes, int n_in,
                              void* d_out, int out_size, void* d_ws, size_t ws_size,
                              hipStream_t stream) {
    const float* x   = (const float*)d_in[0];
    const int*   ei  = (const int*)d_in[1];
    const float* Ws0 = (const float*)d_in[2];
    const float* Wn0 = (const float*)d_in[3];
    const float* b0  = (const float*)d_in[4];
    const float* Ws1 = (const float*)d_in[5];
    const float* Wn1 = (const float*)d_in[6];
    const float* b1  = (const float*)d_in[7];
    const float* Ws2 = (const float*)d_in[8];
    const float* Wn2 = (const float*)d_in[9];
    const float* b2  = (const float*)d_in[10];
    float* out = (float*)d_out;

    const int* src = ei;
    const int* dst = ei + N_EDGES;

    // ---- workspace layout ----
    char* ws = (char*)d_ws;
    float* invdeg     = (float*)ws;   ws += 50176 * 4;
    int*   cnt        = (int*)ws;     ws += 50176 * 4;
    int*   row_ptr    = (int*)ws;     ws += 50432 * 4;
    int*   cursor     = (int*)ws;     ws += 50432 * 4;
    int*   bsum       = (int*)ws;     ws += 256 * 4;
    unsigned* ctr     = (unsigned*)ws; ws += 256 * 4;
    unsigned short* sorted_src = (unsigned short*)ws; ws += 600064 * 2;
    unsigned short* Whi0 = (unsigned short*)ws; ws += 8 * 8 * 64 * 8 * 2;   // 64 KB
    unsigned short* Wlo0 = (unsigned short*)ws; ws += 8 * 8 * 64 * 8 * 2;
    unsigned short* Whi1 = (unsigned short*)ws; ws += 8 * 8 * 64 * 8 * 2;
    unsigned short* Wlo1 = (unsigned short*)ws; ws += 8 * 8 * 64 * 8 * 2;
    unsigned short* Whi2 = (unsigned short*)ws; ws += 8 * 4 * 64 * 8 * 2;   // 32 KB
    unsigned short* Wlo2 = (unsigned short*)ws; ws += 8 * 4 * 64 * 8 * 2;
    unsigned short* hb_a = (unsigned short*)ws; ws += (long)N_NODES * DFEAT * 2; // 12.8 MB
    unsigned short* hb_b = (unsigned short*)ws; ws += (long)N_NODES * DFEAT * 2; // 12.8 MB
    unsigned short* mean_b = (unsigned short*)ws; ws += (long)N_NODES * DFEAT * 2; // 12.8 MB

    // ---- build chain (5 dispatches) ----
    sage_prep_kernel<<<1024, 256, 0, stream>>>(
        x, Ws0, Wn0, Ws1, Wn1, Ws2, Wn2,
        Whi0, Wlo0, Whi1, Wlo1, Whi2, Wlo2, hb_a, cnt, ctr);
    sage_hist_kernel<<<(N_EDGES + 255) / 256, 256, 0, stream>>>(dst, cnt, N_EDGES);
    sage_bsum_kernel<<<SCAN_NB, 256, 0, stream>>>(cnt, bsum, ctr, N_NODES, SCAN_NB);
    sage_scan2_kernel<<<SCAN_NB, 256, 0, stream>>>(cnt, bsum, row_ptr, cursor, invdeg, N_NODES);
    sage_fill_kernel<<<(N_EDGES + 255) / 256, 256, 0, stream>>>(
        src, dst, cursor, sorted_src, N_EDGES);

    const int gather_blocks = (N_NODES + 3) / 4;   // wave per node
    const int mm_blocks = (N_NODES + 31) / 32;     // 1563 single-wave blocks

    // ---- layer 0 ----
    sage_gather_kernel<<<gather_blocks, 256, 0, stream>>>(
        hb_a, row_ptr, sorted_src, invdeg, mean_b, N_NODES);
    sage_mm_mfma_kernel<8, true, false><<<mm_blocks, 64, 0, stream>>>(
        hb_a, mean_b, Whi0, Wlo0, b0, nullptr, hb_b, N_NODES);

    // ---- layer 1 ----
    sage_gather_kernel<<<gather_blocks, 256, 0, stream>>>(
        hb_b, row_ptr, sorted_src, invdeg, mean_b, N_NODES);
    sage_mm_mfma_kernel<8, true, false><<<mm_blocks, 64, 0, stream>>>(
        hb_b, mean_b, Whi1, Wlo1, b1, nullptr, hb_a, N_NODES);

    // ---- layer 2 ----
    sage_gather_kernel<<<gather_blocks, 256, 0, stream>>>(
        hb_a, row_ptr, sorted_src, invdeg, mean_b, N_NODES);
    sage_mm_mfma_kernel<4, false, true><<<mm_blocks, 64, 0, stream>>>(
        hb_a, mean_b, Whi2, Wlo2, b2, out, nullptr, N_NODES);
}